// Round 1
// 287.382 us; speedup vs baseline: 1.1456x; 1.1456x over previous
//
#include <hip/hip_runtime.h>
#include <stdint.h>

typedef short short8 __attribute__((ext_vector_type(8)));
typedef float f32x4 __attribute__((ext_vector_type(4)));
typedef int int2v __attribute__((ext_vector_type(2)));
typedef int int4v __attribute__((ext_vector_type(4)));

// 0.125 (1/sqrt(64)) * log2(e): fold softmax scale + exp2-domain into Q.
#define QSCALE 0.1803368801111137f
// log2(10000)/32
#define FREQC 0.4152410118609203f

__device__ __forceinline__ float bf2f(unsigned short u) {
    union { unsigned int i; float f; } x; x.i = ((unsigned int)u) << 16; return x.f;
}
__device__ __forceinline__ unsigned short f2bf(float f) {
    union { float f; unsigned int i; } x; x.f = f;
    unsigned int i = x.i;
    unsigned int r = i + 0x7FFFu + ((i >> 16) & 1u);   // RNE
    return (unsigned short)(r >> 16);
}
// packed f32x2 -> bf16x2 (RNE); no builtin on gfx950, inline asm per guide T12.
__device__ __forceinline__ int cvtpk_bf16(float lo, float hi) {
    int r;
    asm("v_cvt_pk_bf16_f32 %0, %1, %2" : "=v"(r) : "v"(lo), "v"(hi));
    return r;
}

// async global->LDS, 16B/lane. HW dest = wave-uniform base + lane*16.
#define GLDS16(g, l) \
    __builtin_amdgcn_global_load_lds((const __attribute__((address_space(1))) void*)(g), \
                                     (__attribute__((address_space(3))) void*)(l), 16, 0, 0)

// ---------------- fused fp32 -> bf16 convert for all 4 arrays ----------------
__global__ void cvt_all(const float* __restrict__ hs, const float* __restrict__ k,
                        const float* __restrict__ wq, const float* __restrict__ wo,
                        unsigned short* __restrict__ hs_b, unsigned short* __restrict__ k_b,
                        unsigned short* __restrict__ wq_b, unsigned short* __restrict__ wo_b) {
    int blk = blockIdx.x;
    const float* in; unsigned short* out; int i;
    if (blk < 8192)        { in = hs; out = hs_b; i = blk * 256 + threadIdx.x; }
    else if (blk < 16384)  { in = k;  out = k_b;  i = (blk - 8192) * 256 + threadIdx.x; }
    else if (blk < 20480)  { in = wq; out = wq_b; i = (blk - 16384) * 256 + threadIdx.x; }
    else                   { in = wo; out = wo_b; i = (blk - 20480) * 256 + threadIdx.x; }
    float4 v = ((const float4*)in)[i];
    ushort4 o;
    o.x = f2bf(v.x); o.y = f2bf(v.y); o.z = f2bf(v.z); o.w = f2bf(v.w);
    ((ushort4*)out)[i] = o;
}

// ---------------- V: (B,T,H,D) f32 -> (B,H,D,T) bf16 ----------------
__global__ __launch_bounds__(256) void transpose_v(const float* __restrict__ V, unsigned short* __restrict__ Vt) {
    __shared__ float s[64 * 65];
    int t0 = blockIdx.x * 64;
    int bh = blockIdx.y;           // b*32 + h
    int b = bh >> 5, h = bh & 31;
    int tid = threadIdx.x;
#pragma unroll
    for (int it = 0; it < 4; ++it) {
        int c = tid + it * 256;
        int t = c >> 4;
        int d0 = (c & 15) * 4;
        float4 v = *(const float4*)(V + (size_t)(((b * 2048 + t0 + t) * 32 + h)) * 64 + d0);
        s[t * 65 + d0 + 0] = v.x; s[t * 65 + d0 + 1] = v.y;
        s[t * 65 + d0 + 2] = v.z; s[t * 65 + d0 + 3] = v.w;
    }
    __syncthreads();
#pragma unroll
    for (int it = 0; it < 2; ++it) {
        int c = tid + it * 256;
        int d = c >> 3;
        int tt = (c & 7) * 8;
        short8 pk;
#pragma unroll
        for (int j = 0; j < 8; ++j) pk[j] = (short)f2bf(s[(tt + j) * 65 + d]);
        *(short8*)(Vt + (size_t)(bh * 64 + d) * 2048 + t0 + tt) = pk;
    }
}

// ---------------- bf16 GEMM, C = A * B^T; BK=64, XOR-swizzled LDS, double-buffered ----------------
// 2-phase pipeline (guide T3 minimum): prefetch k0+64 via global_load_lds while
// computing k0; ONE barrier per K-step. LDS 64KB -> 2 blocks/CU = grid residency (512/256).
template <bool BF16_OUT>
__global__ __launch_bounds__(256) void gemm_bt(
    const unsigned short* __restrict__ A,   // M x K bf16
    const unsigned short* __restrict__ B,   // N x K bf16
    void* __restrict__ Cout,                // M x N
    int M, int N, int K)
{
    __shared__ __align__(16) unsigned short lA[2][128 * 64];
    __shared__ __align__(16) unsigned short lB[2][128 * 64];
    int tid = threadIdx.x, lane = tid & 63, wave = tid >> 6;
    int wm = (wave >> 1) * 64, wn = (wave & 1) * 64;
    int m16 = lane & 15, q = lane >> 4;
    int rowBase = blockIdx.x * 128, colBase = blockIdx.y * 128;
    f32x4 acc[4][4] = {};

    int sr = lane >> 3;            // 0..7: row within 8-row group
    int g  = (lane & 7) ^ sr;      // swizzled k-group
    const unsigned short* gAp = A + (size_t)(rowBase + wave * 32 + sr) * K + g * 8;
    const unsigned short* gBp = B + (size_t)(colBase + wave * 32 + sr) * K + g * 8;

#define GSTAGE(buf, k0)                                                                   \
    do {                                                                                  \
        _Pragma("unroll")                                                                 \
        for (int i = 0; i < 4; ++i) {                                                     \
            GLDS16(gAp + (size_t)(8 * i) * K + (k0), &lA[buf][(wave * 32 + 8 * i) * 64]); \
            GLDS16(gBp + (size_t)(8 * i) * K + (k0), &lB[buf][(wave * 32 + 8 * i) * 64]); \
        }                                                                                 \
    } while (0)

    GSTAGE(0, 0);
    __syncthreads();
    int cur = 0;
    for (int k0 = 0; k0 < K; k0 += 64) {
        if (k0 + 64 < K) GSTAGE(cur ^ 1, k0 + 64);   // overlaps with compute below
        const unsigned short* la = lA[cur];
        const unsigned short* lb = lB[cur];
#pragma unroll
        for (int kk = 0; kk < 2; ++kk) {
            short8 af[4], bfr[4];
#pragma unroll
            for (int i = 0; i < 4; ++i) {
                int RA = wm + i * 16 + m16;
                af[i]  = *(const short8*)&la[RA * 64 + (((kk * 4 + q) ^ (RA & 7)) * 8)];
                int RB = wn + i * 16 + m16;
                bfr[i] = *(const short8*)&lb[RB * 64 + (((kk * 4 + q) ^ (RB & 7)) * 8)];
            }
#pragma unroll
            for (int i = 0; i < 4; ++i)
#pragma unroll
                for (int jn = 0; jn < 4; ++jn)
                    acc[i][jn] = __builtin_amdgcn_mfma_f32_16x16x32_bf16(af[i], bfr[jn], acc[i][jn], 0, 0, 0);
        }
        __syncthreads();   // drains prefetch vmcnt + protects buffer swap
        cur ^= 1;
    }
#pragma unroll
    for (int i = 0; i < 4; ++i)
#pragma unroll
        for (int jn = 0; jn < 4; ++jn)
#pragma unroll
            for (int r = 0; r < 4; ++r) {
                int row = rowBase + wm + i * 16 + q * 4 + r;   // C row = quad*4+reg
                int col = colBase + wn + jn * 16 + m16;        // C col = lane&15
                float v = acc[i][jn][r];
                if (BF16_OUT) ((unsigned short*)Cout)[(size_t)row * N + col] = f2bf(v);
                else          ((float*)Cout)[(size_t)row * N + col] = v;
            }
}

// ---------------- flash attention (causal), paired Q-tiles, RoPE fused ----------------
// Rewritten round: swapped QK^T (mfma(K,Q)) => lane (q,m16) holds P[key=nt*16+q*4+r][query=m16].
// PV uses a permuted key order pi(kappa)=(kappa&4?16:0)+(kappa>>3)*4+(kappa&3) applied to BOTH
// operands (any bijection is legal for a dot-product axis), which makes the PV A-fragment the
// lane's OWN exp2 results packed via v_cvt_pk_bf16_f32 -- no sP LDS, no cross-lane ops.
// V-fragment: 4x ds_read_b64 per d-tile at the matching permuted columns (bank-uniform).
// K/V staged with global_load_lds + XOR swizzle, double-buffered, ONE barrier per K-tile.
__global__ __launch_bounds__(256, 4) void attn(
    const unsigned short* __restrict__ Q,   // (B*T) x 2048, raw gemm1 output (no rope)
    const unsigned short* __restrict__ Kb,  // (B*T) x 2048
    const unsigned short* __restrict__ Vt,  // (B*H*64) x 2048  (d-major)
    unsigned short* __restrict__ O)         // (B*T) x 2048
{
    __shared__ __align__(16) unsigned short sK[2][64 * 64];   // rows = key, cols = d (swizzled)
    __shared__ __align__(16) unsigned short sV[2][64 * 64];   // rows = d, cols = key (swizzled)
    int tid = threadIdx.x, lane = tid & 63, w = tid >> 6;
    int m16 = lane & 15, q = lane >> 4;
    int rx = m16 & 7;                        // row&7 for all LDS reads (rows = nt*16+m16)
    int flat = blockIdx.x;
    int bh = flat & 63, p = flat >> 6;
    int b = bh >> 5, h = bh & 31;
    int qtA = 31 - p, qtB = p;

    // Q fragments for both tiles: load, RoPE (interleaved pairs are frag-local), scale.
    // Layout (row = query = m16, k-halves q*8..) serves as MFMA B-operand unchanged.
    short8 aqA0, aqA1, aqB0, aqB1;
    {
        int tA = qtA * 64 + w * 16 + m16;
        int tB = qtB * 64 + w * 16 + m16;
        const unsigned short* rowA = Q + (size_t)(b * 2048 + tA) * 2048 + h * 64 + q * 8;
        const unsigned short* rowB = Q + (size_t)(b * 2048 + tB) * 2048 + h * 64 + q * 8;
        short8 a0 = *(const short8*)rowA, a1 = *(const short8*)(rowA + 32);
        short8 b0 = *(const short8*)rowB, b1 = *(const short8*)(rowB + 32);
        float tfA = (float)tA, tfB = (float)tB;
#pragma unroll
        for (int j = 0; j < 4; ++j) {
            float inv0 = __builtin_amdgcn_exp2f(-FREQC * (float)(q * 4 + j));
            float inv1 = __builtin_amdgcn_exp2f(-FREQC * (float)(16 + q * 4 + j));
            float cA0 = __cosf(tfA * inv0), sA0 = __sinf(tfA * inv0);
            float cA1 = __cosf(tfA * inv1), sA1 = __sinf(tfA * inv1);
            float cB0 = __cosf(tfB * inv0), sB0 = __sinf(tfB * inv0);
            float cB1 = __cosf(tfB * inv1), sB1 = __sinf(tfB * inv1);
            float x1, x2;
            x1 = bf2f((unsigned short)a0[2 * j]); x2 = bf2f((unsigned short)a0[2 * j + 1]);
            aqA0[2 * j]     = (short)f2bf((x1 * cA0 - x2 * sA0) * QSCALE);
            aqA0[2 * j + 1] = (short)f2bf((x1 * sA0 + x2 * cA0) * QSCALE);
            x1 = bf2f((unsigned short)a1[2 * j]); x2 = bf2f((unsigned short)a1[2 * j + 1]);
            aqA1[2 * j]     = (short)f2bf((x1 * cA1 - x2 * sA1) * QSCALE);
            aqA1[2 * j + 1] = (short)f2bf((x1 * sA1 + x2 * cA1) * QSCALE);
            x1 = bf2f((unsigned short)b0[2 * j]); x2 = bf2f((unsigned short)b0[2 * j + 1]);
            aqB0[2 * j]     = (short)f2bf((x1 * cB0 - x2 * sB0) * QSCALE);
            aqB0[2 * j + 1] = (short)f2bf((x1 * sB0 + x2 * cB0) * QSCALE);
            x1 = bf2f((unsigned short)b1[2 * j]); x2 = bf2f((unsigned short)b1[2 * j + 1]);
            aqB1[2 * j]     = (short)f2bf((x1 * cB1 - x2 * sB1) * QSCALE);
            aqB1[2 * j + 1] = (short)f2bf((x1 * sB1 + x2 * cB1) * QSCALE);
        }
    }

    float lrunA = 0.f, lrunB = 0.f;          // per-lane denominator partial for query m16
    f32x4 accOA[4], accOB[4];
#pragma unroll
    for (int nt = 0; nt < 4; ++nt) {
        f32x4 z = {0.f, 0.f, 0.f, 0.f};
        accOA[nt] = z; accOB[nt] = z;
    }

    // staging: wave w stages K rows / V d-rows [w*16, w*16+16). 8 rows per GLDS.
    // swizzle: slot (lane&7) holds global col-group (lane&7)^sr, sr = row&7.
    int sr = lane >> 3, g = (lane & 7) ^ sr;
    int rb = w * 16;
    const unsigned short* kgp = Kb + (size_t)(b * 2048 + rb + sr) * 2048 + h * 64 + g * 8;
    const unsigned short* vgp = Vt + (size_t)((b * 32 + h) * 64 + rb + sr) * 2048 + g * 8;

#define ASTAGE(kt, bi)                                                              \
    do {                                                                            \
        int kb0 = (kt) * 64;                                                        \
        _Pragma("unroll")                                                           \
        for (int i = 0; i < 2; ++i) {                                               \
            GLDS16(kgp + (size_t)(kb0 + 8 * i) * 2048, &sK[bi][(rb + 8 * i) * 64]); \
            GLDS16(vgp + (size_t)(8 * i) * 2048 + kb0, &sV[bi][(rb + 8 * i) * 64]); \
        }                                                                           \
    } while (0)

    ASTAGE(0, 0);
    __syncthreads();
    int cur = 0;
    for (int kt = 0; kt <= qtA; ++kt) {
        if (kt < qtA) ASTAGE(kt + 1, cur ^ 1);       // overlaps with compute
        bool doB = (kt <= qtB);
        bool diagA = (kt == qtA), diagB = (kt == qtB);
        const unsigned short* kbuf = sK[cur];
        const unsigned short* vbuf = sV[cur];

        // ---- QK^T (swapped) + softmax, P packed in registers ----
        int pkA[4][2], pkB[4][2];
#pragma unroll
        for (int nt = 0; nt < 4; ++nt) {
            const unsigned short* kr = kbuf + (nt * 16 + m16) * 64;
            short8 bk0 = *(const short8*)&kr[(q ^ rx) * 8];          // dims 0..31, slice q*8
            short8 bk1 = *(const short8*)&kr[((4 + q) ^ rx) * 8];    // dims 32..63
            f32x4 zA = {0.f, 0.f, 0.f, 0.f};
            zA = __builtin_amdgcn_mfma_f32_16x16x32_bf16(bk0, aqA0, zA, 0, 0, 0);
            zA = __builtin_amdgcn_mfma_f32_16x16x32_bf16(bk1, aqA1, zA, 0, 0, 0);
            float e[4];
#pragma unroll
            for (int r = 0; r < 4; ++r) {
                float s = zA[r];                                      // P[key nt*16+q*4+r][query m16]
                if (diagA && (nt * 16 + q * 4 + r > w * 16 + m16)) s = -__builtin_inff();
                e[r] = __builtin_amdgcn_exp2f(s);
            }
            lrunA += (e[0] + e[1]) + (e[2] + e[3]);
            pkA[nt][0] = cvtpk_bf16(e[0], e[1]);
            pkA[nt][1] = cvtpk_bf16(e[2], e[3]);
            if (doB) {
                f32x4 zB = {0.f, 0.f, 0.f, 0.f};
                zB = __builtin_amdgcn_mfma_f32_16x16x32_bf16(bk0, aqB0, zB, 0, 0, 0);
                zB = __builtin_amdgcn_mfma_f32_16x16x32_bf16(bk1, aqB1, zB, 0, 0, 0);
                float eb[4];
#pragma unroll
                for (int r = 0; r < 4; ++r) {
                    float s = zB[r];
                    if (diagB && (nt * 16 + q * 4 + r > w * 16 + m16)) s = -__builtin_inff();
                    eb[r] = __builtin_amdgcn_exp2f(s);
                }
                lrunB += (eb[0] + eb[1]) + (eb[2] + eb[3]);
                pkB[nt][0] = cvtpk_bf16(eb[0], eb[1]);
                pkB[nt][1] = cvtpk_bf16(eb[2], eb[3]);
            }
        }

        // PV A-fragments: permuted key order makes them the lane's own packed values.
        // kappa j=0..3 -> key q*4+j (block nt even), j=4..7 -> key 16+q*4+(j-4) (block nt odd).
        int4v tA0 = {pkA[0][0], pkA[0][1], pkA[1][0], pkA[1][1]};
        int4v tA1 = {pkA[2][0], pkA[2][1], pkA[3][0], pkA[3][1]};
        short8 apA0 = __builtin_bit_cast(short8, tA0);
        short8 apA1 = __builtin_bit_cast(short8, tA1);
        short8 apB0, apB1;
        if (doB) {
            int4v tB0 = {pkB[0][0], pkB[0][1], pkB[1][0], pkB[1][1]};
            int4v tB1 = {pkB[2][0], pkB[2][1], pkB[3][0], pkB[3][1]};
            apB0 = __builtin_bit_cast(short8, tB0);
            apB1 = __builtin_bit_cast(short8, tB1);
        }

        // ---- PV: V fragment at permuted key columns, 4x ds_read_b64 per d-tile ----
#pragma unroll
        for (int nt = 0; nt < 4; ++nt) {
            const unsigned short* vr = vbuf + (nt * 16 + m16) * 64;   // row = d
            int2v a0 = *(const int2v*)&vr[(((q >> 1) + 0) ^ rx) * 8 + (q & 1) * 4]; // keys q*4+0..3
            int2v a1 = *(const int2v*)&vr[(((q >> 1) + 2) ^ rx) * 8 + (q & 1) * 4]; // keys 16+q*4..
            int2v a2 = *(const int2v*)&vr[(((q >> 1) + 4) ^ rx) * 8 + (q & 1) * 4]; // keys 32+q*4..
            int2v a3 = *(const int2v*)&vr[(((q >> 1) + 6) ^ rx) * 8 + (q & 1) * 4]; // keys 48+q*4..
            int4v tv0 = {a0.x, a0.y, a1.x, a1.y};
            int4v tv1 = {a2.x, a2.y, a3.x, a3.y};
            short8 bv0 = __builtin_bit_cast(short8, tv0);
            short8 bv1 = __builtin_bit_cast(short8, tv1);
            accOA[nt] = __builtin_amdgcn_mfma_f32_16x16x32_bf16(apA0, bv0, accOA[nt], 0, 0, 0);
            accOA[nt] = __builtin_amdgcn_mfma_f32_16x16x32_bf16(apA1, bv1, accOA[nt], 0, 0, 0);
            if (doB) {
                accOB[nt] = __builtin_amdgcn_mfma_f32_16x16x32_bf16(apB0, bv0, accOB[nt], 0, 0, 0);
                accOB[nt] = __builtin_amdgcn_mfma_f32_16x16x32_bf16(apB1, bv1, accOB[nt], 0, 0, 0);
            }
        }
        __syncthreads();       // drains prefetch vmcnt + protects buffer swap
        cur ^= 1;
    }

    // denominator: reduce over the 4 q-lanes holding the same query (xor bits 4,5),
    // then redistribute 1/l from query=m16 ownership to the output rows q*4+r.
    lrunA += __shfl_xor(lrunA, 16); lrunA += __shfl_xor(lrunA, 32);
    lrunB += __shfl_xor(lrunB, 16); lrunB += __shfl_xor(lrunB, 32);
    float invA = 1.0f / lrunA, invB = 1.0f / lrunB;
    float nA[4], nB[4];
#pragma unroll
    for (int r = 0; r < 4; ++r) {
        nA[r] = __shfl(invA, q * 4 + r);
        nB[r] = __shfl(invB, q * 4 + r);
    }
#pragma unroll
    for (int nt = 0; nt < 4; ++nt)
#pragma unroll
        for (int r = 0; r < 4; ++r) {
            int col = h * 64 + nt * 16 + m16;
            O[(size_t)(b * 2048 + qtA * 64 + w * 16 + q * 4 + r) * 2048 + col] =
                f2bf(accOA[nt][r] * nA[r]);
            O[(size_t)(b * 2048 + qtB * 64 + w * 16 + q * 4 + r) * 2048 + col] =
                f2bf(accOB[nt][r] * nB[r]);
        }
}

// ---------------- host launcher ----------------
extern "C" void kernel_launch(void* const* d_in, const int* in_sizes, int n_in,
                              void* d_out, int out_size, void* d_ws, size_t ws_size,
                              hipStream_t stream) {
    const float* hs = (const float*)d_in[0];   // (2,2048,2048)
    const float* sk = (const float*)d_in[1];   // (2,2048,32,64)
    const float* sv = (const float*)d_in[2];   // (2,2048,32,64)
    const float* wq = (const float*)d_in[3];   // (2048,2048)
    const float* wo = (const float*)d_in[4];   // (2048,2048)
    float* out = (float*)d_out;

    char* ws = (char*)d_ws;
    unsigned short* hid_b = (unsigned short*)(ws);                              // 16 MiB
    unsigned short* wq_b  = (unsigned short*)(ws + ((size_t)16 << 20));         //  8 MiB
    unsigned short* wo_b  = (unsigned short*)(ws + ((size_t)24 << 20));         //  8 MiB
    unsigned short* k_b   = (unsigned short*)(ws + ((size_t)32 << 20));         // 16 MiB
    unsigned short* vt_b  = (unsigned short*)(ws + ((size_t)48 << 20));         // 16 MiB
    unsigned short* q_b   = (unsigned short*)(ws + ((size_t)64 << 20));         // 16 MiB
    unsigned short* o_b   = (unsigned short*)(ws + ((size_t)80 << 20));         // 16 MiB

    cvt_all<<<24576, 256, 0, stream>>>(hs, sk, wq, wo, hid_b, k_b, wq_b, wo_b);
    transpose_v<<<dim3(32, 64), 256, 0, stream>>>(sv, vt_b);
    gemm_bt<true><<<dim3(32, 16), 256, 0, stream>>>(hid_b, wq_b, (void*)q_b, 4096, 2048, 2048);
    attn<<<1024, 256, 0, stream>>>(q_b, k_b, vt_b, o_b);
    gemm_bt<false><<<dim3(32, 16), 256, 0, stream>>>(o_b, wo_b, (void*)out, 4096, 2048, 2048);
}

// Round 2
// 285.523 us; speedup vs baseline: 1.1531x; 1.0065x over previous
//
#include <hip/hip_runtime.h>
#include <stdint.h>

typedef short short8 __attribute__((ext_vector_type(8)));
typedef float f32x4 __attribute__((ext_vector_type(4)));
typedef int int2v __attribute__((ext_vector_type(2)));
typedef int int4v __attribute__((ext_vector_type(4)));

// 0.125 (1/sqrt(64)) * log2(e): fold softmax scale + exp2-domain into Q.
#define QSCALE 0.1803368801111137f
// log2(10000)/32
#define FREQC 0.4152410118609203f

__device__ __forceinline__ float bf2f(unsigned short u) {
    union { unsigned int i; float f; } x; x.i = ((unsigned int)u) << 16; return x.f;
}
__device__ __forceinline__ unsigned short f2bf(float f) {
    union { float f; unsigned int i; } x; x.f = f;
    unsigned int i = x.i;
    unsigned int r = i + 0x7FFFu + ((i >> 16) & 1u);   // RNE
    return (unsigned short)(r >> 16);
}
// packed f32x2 -> bf16x2 (RNE); no builtin on gfx950, inline asm per guide T12.
__device__ __forceinline__ int cvtpk_bf16(float lo, float hi) {
    int r;
    asm("v_cvt_pk_bf16_f32 %0, %1, %2" : "=v"(r) : "v"(lo), "v"(hi));
    return r;
}

// async global->LDS, 16B/lane. HW dest = wave-uniform base + lane*16.
#define GLDS16(g, l) \
    __builtin_amdgcn_global_load_lds((const __attribute__((address_space(1))) void*)(g), \
                                     (__attribute__((address_space(3))) void*)(l), 16, 0, 0)

// counted vmcnt waits (T4): loads stay in flight across barriers; never drain
// to 0 in the steady-state loop. "memory" clobber pins GLDS issue before /
// ds_read after.
#define WAITVM(n) asm volatile("s_waitcnt vmcnt(" #n ")" ::: "memory")

// ---------------- fused fp32->bf16 convert (4 arrays) + V transpose, one launch ----------------
// blocks [0,24576): elementwise cvt; blocks [24576,26624): V (B,T,H,D) -> (B,H,D,T) bf16.
__global__ __launch_bounds__(256) void cvt_tr(
    const float* __restrict__ hs, const float* __restrict__ k,
    const float* __restrict__ wq, const float* __restrict__ wo,
    const float* __restrict__ V,
    unsigned short* __restrict__ hs_b, unsigned short* __restrict__ k_b,
    unsigned short* __restrict__ wq_b, unsigned short* __restrict__ wo_b,
    unsigned short* __restrict__ Vt) {
    __shared__ float s[64 * 65];
    int blk = blockIdx.x;
    int tid = threadIdx.x;
    if (blk < 24576) {
        const float* in; unsigned short* out; int i;
        if (blk < 8192)        { in = hs; out = hs_b; i = blk * 256 + tid; }
        else if (blk < 16384)  { in = k;  out = k_b;  i = (blk - 8192) * 256 + tid; }
        else if (blk < 20480)  { in = wq; out = wq_b; i = (blk - 16384) * 256 + tid; }
        else                   { in = wo; out = wo_b; i = (blk - 20480) * 256 + tid; }
        float4 v = ((const float4*)in)[i];
        ushort4 o;
        o.x = f2bf(v.x); o.y = f2bf(v.y); o.z = f2bf(v.z); o.w = f2bf(v.w);
        ((ushort4*)out)[i] = o;
        return;
    }
    int tb = blk - 24576;          // 0..2047
    int t0 = (tb & 31) * 64;
    int bh = tb >> 5;              // b*32 + h
    int b = bh >> 5, h = bh & 31;
#pragma unroll
    for (int it = 0; it < 4; ++it) {
        int c = tid + it * 256;
        int t = c >> 4;
        int d0 = (c & 15) * 4;
        float4 v = *(const float4*)(V + (size_t)(((b * 2048 + t0 + t) * 32 + h)) * 64 + d0);
        s[t * 65 + d0 + 0] = v.x; s[t * 65 + d0 + 1] = v.y;
        s[t * 65 + d0 + 2] = v.z; s[t * 65 + d0 + 3] = v.w;
    }
    __syncthreads();
#pragma unroll
    for (int it = 0; it < 2; ++it) {
        int c = tid + it * 256;
        int d = c >> 3;
        int tt = (c & 7) * 8;
        short8 pk;
#pragma unroll
        for (int j = 0; j < 8; ++j) pk[j] = (short)f2bf(s[(tt + j) * 65 + d]);
        *(short8*)(Vt + (size_t)(bh * 64 + d) * 2048 + t0 + tt) = pk;
    }
}

// ---------------- bf16 GEMM, C = A * B^T; BK=64, XOR-swizzled LDS, double-buffered ----------------
// Counted-vmcnt pipeline (T3+T4): prefetch issued at top of step t, waited with
// vmcnt(8) at top of step t+1 -> in-flight window spans the whole compute phase.
// Raw s_barrier (no implicit vmcnt(0) drain, unlike __syncthreads).
// Hazards: iter t's GSTAGE writes buf^1; last reads of buf^1 were iter t-1's
// compute, separated by t-1's trailing barrier. Reads of buf[cur] in iter t are
// separated from iter t+1's writes to it by t's trailing barrier.
template <bool BF16_OUT>
__global__ __launch_bounds__(256) void gemm_bt(
    const unsigned short* __restrict__ A,   // M x K bf16
    const unsigned short* __restrict__ B,   // N x K bf16
    void* __restrict__ Cout,                // M x N
    int M, int N, int K)
{
    __shared__ __align__(16) unsigned short lA[2][128 * 64];
    __shared__ __align__(16) unsigned short lB[2][128 * 64];
    int tid = threadIdx.x, lane = tid & 63, wave = tid >> 6;
    int wm = (wave >> 1) * 64, wn = (wave & 1) * 64;
    int m16 = lane & 15, q = lane >> 4;
    int rowBase = blockIdx.x * 128, colBase = blockIdx.y * 128;
    f32x4 acc[4][4] = {};

    int sr = lane >> 3;            // 0..7: row within 8-row group
    int g  = (lane & 7) ^ sr;      // swizzled k-group
    const unsigned short* gAp = A + (size_t)(rowBase + wave * 32 + sr) * K + g * 8;
    const unsigned short* gBp = B + (size_t)(colBase + wave * 32 + sr) * K + g * 8;

#define GSTAGE(buf, k0)                                                                   \
    do {                                                                                  \
        _Pragma("unroll")                                                                 \
        for (int i = 0; i < 4; ++i) {                                                     \
            GLDS16(gAp + (size_t)(8 * i) * K + (k0), &lA[buf][(wave * 32 + 8 * i) * 64]); \
            GLDS16(gBp + (size_t)(8 * i) * K + (k0), &lB[buf][(wave * 32 + 8 * i) * 64]); \
        }                                                                                 \
    } while (0)

    GSTAGE(0, 0);
    WAITVM(0);
    __builtin_amdgcn_s_barrier();
    int cur = 0;
    for (int k0 = 0; k0 < K; k0 += 64) {
        if (k0 + 64 < K) {
            GSTAGE(cur ^ 1, k0 + 64);   // 8 loads stay in flight through compute
            WAITVM(8);                  // tile-k0's 8 (oldest) have landed
        } else {
            WAITVM(0);                  // final tile: full drain
        }
        __builtin_amdgcn_s_barrier();   // all waves' tile-k0 loads complete
        const unsigned short* la = lA[cur];
        const unsigned short* lb = lB[cur];
#pragma unroll
        for (int kk = 0; kk < 2; ++kk) {
            short8 af[4], bfr[4];
#pragma unroll
            for (int i = 0; i < 4; ++i) {
                int RA = wm + i * 16 + m16;
                af[i]  = *(const short8*)&la[RA * 64 + (((kk * 4 + q) ^ (RA & 7)) * 8)];
                int RB = wn + i * 16 + m16;
                bfr[i] = *(const short8*)&lb[RB * 64 + (((kk * 4 + q) ^ (RB & 7)) * 8)];
            }
#pragma unroll
            for (int i = 0; i < 4; ++i)
#pragma unroll
                for (int jn = 0; jn < 4; ++jn)
                    acc[i][jn] = __builtin_amdgcn_mfma_f32_16x16x32_bf16(af[i], bfr[jn], acc[i][jn], 0, 0, 0);
        }
        __builtin_amdgcn_s_barrier();   // reads done before next iter overwrites buf^1
        cur ^= 1;
    }
#pragma unroll
    for (int i = 0; i < 4; ++i)
#pragma unroll
        for (int jn = 0; jn < 4; ++jn)
#pragma unroll
            for (int r = 0; r < 4; ++r) {
                int row = rowBase + wm + i * 16 + q * 4 + r;   // C row = quad*4+reg
                int col = colBase + wn + jn * 16 + m16;        // C col = lane&15
                float v = acc[i][jn][r];
                if (BF16_OUT) ((unsigned short*)Cout)[(size_t)row * N + col] = f2bf(v);
                else          ((float*)Cout)[(size_t)row * N + col] = v;
            }
}

// ---------------- flash attention (causal), paired Q-tiles, RoPE fused ----------------
// Swapped QK^T (mfma(K,Q)) => lane (q,m16) holds P[key=nt*16+q*4+r][query=m16].
// PV uses a permuted key order pi applied to BOTH operands, making the PV
// A-fragment the lane's OWN exp2 results packed via v_cvt_pk_bf16_f32 -- no sP
// LDS, no cross-lane ops. K/V staged with global_load_lds + XOR swizzle,
// double-buffered; counted vmcnt(4) + raw barriers (same hazard proof as gemm).
__global__ __launch_bounds__(256, 4) void attn(
    const unsigned short* __restrict__ Q,   // (B*T) x 2048, raw gemm1 output (no rope)
    const unsigned short* __restrict__ Kb,  // (B*T) x 2048
    const unsigned short* __restrict__ Vt,  // (B*H*64) x 2048  (d-major)
    unsigned short* __restrict__ O)         // (B*T) x 2048
{
    __shared__ __align__(16) unsigned short sK[2][64 * 64];   // rows = key, cols = d (swizzled)
    __shared__ __align__(16) unsigned short sV[2][64 * 64];   // rows = d, cols = key (swizzled)
    int tid = threadIdx.x, lane = tid & 63, w = tid >> 6;
    int m16 = lane & 15, q = lane >> 4;
    int rx = m16 & 7;                        // row&7 for all LDS reads (rows = nt*16+m16)
    int flat = blockIdx.x;
    int bh = flat & 63, p = flat >> 6;       // flat%8==bh%8 -> (b,h) pinned to one XCD
    int b = bh >> 5, h = bh & 31;
    int qtA = 31 - p, qtB = p;

    // Q fragments for both tiles: load, RoPE (interleaved pairs are frag-local), scale.
    short8 aqA0, aqA1, aqB0, aqB1;
    {
        int tA = qtA * 64 + w * 16 + m16;
        int tB = qtB * 64 + w * 16 + m16;
        const unsigned short* rowA = Q + (size_t)(b * 2048 + tA) * 2048 + h * 64 + q * 8;
        const unsigned short* rowB = Q + (size_t)(b * 2048 + tB) * 2048 + h * 64 + q * 8;
        short8 a0 = *(const short8*)rowA, a1 = *(const short8*)(rowA + 32);
        short8 b0 = *(const short8*)rowB, b1 = *(const short8*)(rowB + 32);
        float tfA = (float)tA, tfB = (float)tB;
#pragma unroll
        for (int j = 0; j < 4; ++j) {
            float inv0 = __builtin_amdgcn_exp2f(-FREQC * (float)(q * 4 + j));
            float inv1 = __builtin_amdgcn_exp2f(-FREQC * (float)(16 + q * 4 + j));
            float cA0 = __cosf(tfA * inv0), sA0 = __sinf(tfA * inv0);
            float cA1 = __cosf(tfA * inv1), sA1 = __sinf(tfA * inv1);
            float cB0 = __cosf(tfB * inv0), sB0 = __sinf(tfB * inv0);
            float cB1 = __cosf(tfB * inv1), sB1 = __sinf(tfB * inv1);
            float x1, x2;
            x1 = bf2f((unsigned short)a0[2 * j]); x2 = bf2f((unsigned short)a0[2 * j + 1]);
            aqA0[2 * j]     = (short)f2bf((x1 * cA0 - x2 * sA0) * QSCALE);
            aqA0[2 * j + 1] = (short)f2bf((x1 * sA0 + x2 * cA0) * QSCALE);
            x1 = bf2f((unsigned short)a1[2 * j]); x2 = bf2f((unsigned short)a1[2 * j + 1]);
            aqA1[2 * j]     = (short)f2bf((x1 * cA1 - x2 * sA1) * QSCALE);
            aqA1[2 * j + 1] = (short)f2bf((x1 * sA1 + x2 * cA1) * QSCALE);
            x1 = bf2f((unsigned short)b0[2 * j]); x2 = bf2f((unsigned short)b0[2 * j + 1]);
            aqB0[2 * j]     = (short)f2bf((x1 * cB0 - x2 * sB0) * QSCALE);
            aqB0[2 * j + 1] = (short)f2bf((x1 * sB0 + x2 * cB0) * QSCALE);
            x1 = bf2f((unsigned short)b1[2 * j]); x2 = bf2f((unsigned short)b1[2 * j + 1]);
            aqB1[2 * j]     = (short)f2bf((x1 * cB1 - x2 * sB1) * QSCALE);
            aqB1[2 * j + 1] = (short)f2bf((x1 * sB1 + x2 * cB1) * QSCALE);
        }
    }

    float lrunA = 0.f, lrunB = 0.f;          // per-lane denominator partial for query m16
    f32x4 accOA[4], accOB[4];
#pragma unroll
    for (int nt = 0; nt < 4; ++nt) {
        f32x4 z = {0.f, 0.f, 0.f, 0.f};
        accOA[nt] = z; accOB[nt] = z;
    }

    // staging: wave w stages K rows / V d-rows [w*16, w*16+16). 8 rows per GLDS.
    // swizzle: slot (lane&7) holds global col-group (lane&7)^sr, sr = row&7.
    int sr = lane >> 3, g = (lane & 7) ^ sr;
    int rb = w * 16;
    const unsigned short* kgp = Kb + (size_t)(b * 2048 + rb + sr) * 2048 + h * 64 + g * 8;
    const unsigned short* vgp = Vt + (size_t)((b * 32 + h) * 64 + rb + sr) * 2048 + g * 8;

#define ASTAGE(kt, bi)                                                              \
    do {                                                                            \
        int kb0 = (kt) * 64;                                                        \
        _Pragma("unroll")                                                           \
        for (int i = 0; i < 2; ++i) {                                               \
            GLDS16(kgp + (size_t)(kb0 + 8 * i) * 2048, &sK[bi][(rb + 8 * i) * 64]); \
            GLDS16(vgp + (size_t)(8 * i) * 2048 + kb0, &sV[bi][(rb + 8 * i) * 64]); \
        }                                                                           \
    } while (0)

    ASTAGE(0, 0);
    WAITVM(0);
    __builtin_amdgcn_s_barrier();
    int cur = 0;
    for (int kt = 0; kt <= qtA; ++kt) {
        if (kt < qtA) {
            ASTAGE(kt + 1, cur ^ 1);    // 4 loads stay in flight through compute
            WAITVM(4);                  // tile-kt's 4 (oldest) have landed
        } else {
            WAITVM(0);
        }
        __builtin_amdgcn_s_barrier();
        bool doB = (kt <= qtB);
        bool diagA = (kt == qtA), diagB = (kt == qtB);
        const unsigned short* kbuf = sK[cur];
        const unsigned short* vbuf = sV[cur];

        // ---- QK^T (swapped) + softmax, P packed in registers ----
        int pkA[4][2], pkB[4][2];
#pragma unroll
        for (int nt = 0; nt < 4; ++nt) {
            const unsigned short* kr = kbuf + (nt * 16 + m16) * 64;
            short8 bk0 = *(const short8*)&kr[(q ^ rx) * 8];          // dims 0..31, slice q*8
            short8 bk1 = *(const short8*)&kr[((4 + q) ^ rx) * 8];    // dims 32..63
            f32x4 zA = {0.f, 0.f, 0.f, 0.f};
            zA = __builtin_amdgcn_mfma_f32_16x16x32_bf16(bk0, aqA0, zA, 0, 0, 0);
            zA = __builtin_amdgcn_mfma_f32_16x16x32_bf16(bk1, aqA1, zA, 0, 0, 0);
            float e[4];
#pragma unroll
            for (int r = 0; r < 4; ++r) {
                float s = zA[r];                                      // P[key nt*16+q*4+r][query m16]
                if (diagA && (nt * 16 + q * 4 + r > w * 16 + m16)) s = -__builtin_inff();
                e[r] = __builtin_amdgcn_exp2f(s);
            }
            lrunA += (e[0] + e[1]) + (e[2] + e[3]);
            pkA[nt][0] = cvtpk_bf16(e[0], e[1]);
            pkA[nt][1] = cvtpk_bf16(e[2], e[3]);
            if (doB) {
                f32x4 zB = {0.f, 0.f, 0.f, 0.f};
                zB = __builtin_amdgcn_mfma_f32_16x16x32_bf16(bk0, aqB0, zB, 0, 0, 0);
                zB = __builtin_amdgcn_mfma_f32_16x16x32_bf16(bk1, aqB1, zB, 0, 0, 0);
                float eb[4];
#pragma unroll
                for (int r = 0; r < 4; ++r) {
                    float s = zB[r];
                    if (diagB && (nt * 16 + q * 4 + r > w * 16 + m16)) s = -__builtin_inff();
                    eb[r] = __builtin_amdgcn_exp2f(s);
                }
                lrunB += (eb[0] + eb[1]) + (eb[2] + eb[3]);
                pkB[nt][0] = cvtpk_bf16(eb[0], eb[1]);
                pkB[nt][1] = cvtpk_bf16(eb[2], eb[3]);
            }
        }

        // PV A-fragments: permuted key order makes them the lane's own packed values.
        int4v tA0 = {pkA[0][0], pkA[0][1], pkA[1][0], pkA[1][1]};
        int4v tA1 = {pkA[2][0], pkA[2][1], pkA[3][0], pkA[3][1]};
        short8 apA0 = __builtin_bit_cast(short8, tA0);
        short8 apA1 = __builtin_bit_cast(short8, tA1);
        short8 apB0, apB1;
        if (doB) {
            int4v tB0 = {pkB[0][0], pkB[0][1], pkB[1][0], pkB[1][1]};
            int4v tB1 = {pkB[2][0], pkB[2][1], pkB[3][0], pkB[3][1]};
            apB0 = __builtin_bit_cast(short8, tB0);
            apB1 = __builtin_bit_cast(short8, tB1);
        }

        // ---- PV: V fragment at permuted key columns, 4x ds_read_b64 per d-tile ----
#pragma unroll
        for (int nt = 0; nt < 4; ++nt) {
            const unsigned short* vr = vbuf + (nt * 16 + m16) * 64;   // row = d
            int2v a0 = *(const int2v*)&vr[(((q >> 1) + 0) ^ rx) * 8 + (q & 1) * 4]; // keys q*4+0..3
            int2v a1 = *(const int2v*)&vr[(((q >> 1) + 2) ^ rx) * 8 + (q & 1) * 4]; // keys 16+q*4..
            int2v a2 = *(const int2v*)&vr[(((q >> 1) + 4) ^ rx) * 8 + (q & 1) * 4]; // keys 32+q*4..
            int2v a3 = *(const int2v*)&vr[(((q >> 1) + 6) ^ rx) * 8 + (q & 1) * 4]; // keys 48+q*4..
            int4v tv0 = {a0.x, a0.y, a1.x, a1.y};
            int4v tv1 = {a2.x, a2.y, a3.x, a3.y};
            short8 bv0 = __builtin_bit_cast(short8, tv0);
            short8 bv1 = __builtin_bit_cast(short8, tv1);
            accOA[nt] = __builtin_amdgcn_mfma_f32_16x16x32_bf16(apA0, bv0, accOA[nt], 0, 0, 0);
            accOA[nt] = __builtin_amdgcn_mfma_f32_16x16x32_bf16(apA1, bv1, accOA[nt], 0, 0, 0);
            if (doB) {
                accOB[nt] = __builtin_amdgcn_mfma_f32_16x16x32_bf16(apB0, bv0, accOB[nt], 0, 0, 0);
                accOB[nt] = __builtin_amdgcn_mfma_f32_16x16x32_bf16(apB1, bv1, accOB[nt], 0, 0, 0);
            }
        }
        __builtin_amdgcn_s_barrier();   // reads done before next iter overwrites buf^1
        cur ^= 1;
    }

    // denominator: reduce over the 4 q-lanes holding the same query (xor bits 4,5),
    // then redistribute 1/l from query=m16 ownership to the output rows q*4+r.
    lrunA += __shfl_xor(lrunA, 16); lrunA += __shfl_xor(lrunA, 32);
    lrunB += __shfl_xor(lrunB, 16); lrunB += __shfl_xor(lrunB, 32);
    float invA = 1.0f / lrunA, invB = 1.0f / lrunB;
    float nA[4], nB[4];
#pragma unroll
    for (int r = 0; r < 4; ++r) {
        nA[r] = __shfl(invA, q * 4 + r);
        nB[r] = __shfl(invB, q * 4 + r);
    }
#pragma unroll
    for (int nt = 0; nt < 4; ++nt)
#pragma unroll
        for (int r = 0; r < 4; ++r) {
            int col = h * 64 + nt * 16 + m16;
            O[(size_t)(b * 2048 + qtA * 64 + w * 16 + q * 4 + r) * 2048 + col] =
                f2bf(accOA[nt][r] * nA[r]);
            O[(size_t)(b * 2048 + qtB * 64 + w * 16 + q * 4 + r) * 2048 + col] =
                f2bf(accOB[nt][r] * nB[r]);
        }
}

// ---------------- host launcher ----------------
extern "C" void kernel_launch(void* const* d_in, const int* in_sizes, int n_in,
                              void* d_out, int out_size, void* d_ws, size_t ws_size,
                              hipStream_t stream) {
    const float* hs = (const float*)d_in[0];   // (2,2048,2048)
    const float* sk = (const float*)d_in[1];   // (2,2048,32,64)
    const float* sv = (const float*)d_in[2];   // (2,2048,32,64)
    const float* wq = (const float*)d_in[3];   // (2048,2048)
    const float* wo = (const float*)d_in[4];   // (2048,2048)
    float* out = (float*)d_out;

    char* ws = (char*)d_ws;
    unsigned short* hid_b = (unsigned short*)(ws);                              // 16 MiB
    unsigned short* wq_b  = (unsigned short*)(ws + ((size_t)16 << 20));         //  8 MiB
    unsigned short* wo_b  = (unsigned short*)(ws + ((size_t)24 << 20));         //  8 MiB
    unsigned short* k_b   = (unsigned short*)(ws + ((size_t)32 << 20));         // 16 MiB
    unsigned short* vt_b  = (unsigned short*)(ws + ((size_t)48 << 20));         // 16 MiB
    unsigned short* q_b   = (unsigned short*)(ws + ((size_t)64 << 20));         // 16 MiB
    unsigned short* o_b   = (unsigned short*)(ws + ((size_t)80 << 20));         // 16 MiB

    cvt_tr<<<26624, 256, 0, stream>>>(hs, sk, wq, wo, sv, hid_b, k_b, wq_b, wo_b, vt_b);
    gemm_bt<true><<<dim3(32, 16), 256, 0, stream>>>(hid_b, wq_b, (void*)q_b, 4096, 2048, 2048);
    attn<<<1024, 256, 0, stream>>>(q_b, k_b, vt_b, o_b);
    gemm_bt<false><<<dim3(32, 16), 256, 0, stream>>>(o_b, wo_b, (void*)out, 4096, 2048, 2048);
}